// Round 9
// baseline (270.531 us; speedup 1.0000x reference)
//
#include <hip/hip_runtime.h>

#define CDIM 256
#define HW 1024            // 32*32
#define NROWS 32768        // 32*1024
#define KCODES 1024
#define ZQ_ELEMS 8388608   // 32*256*1024
#define IDX_OFF ZQ_ELEMS
#define LOSS_OFF (ZQ_ELEMS + NROWS)
#define FLT_BIG 3.402823466e+38f
#define ZT_OFF 5513232ull  // 16B-aligned; z_t fp32 [32768][256] = 32 MB (ws-guarded)

typedef _Float16 f16;
typedef _Float16 f16x8 __attribute__((ext_vector_type(8)));
typedef float f32x4 __attribute__((ext_vector_type(4)));
typedef float f32x16 __attribute__((ext_vector_type(16)));

// async global->LDS, 16 B per lane; LDS dest = wave-uniform base + lane*16
__device__ __forceinline__ void glds16(const void* g, void* l) {
    __builtin_amdgcn_global_load_lds(
        (const __attribute__((address_space(1))) unsigned int*)g,
        (__attribute__((address_space(3))) unsigned int*)l,
        16, 0, 0);
}

__device__ __forceinline__ unsigned int pack_f16x2(f16 a, f16 b) {
    unsigned short ua = *(unsigned short*)&a, ub = *(unsigned short*)&b;
    return (unsigned int)ua | ((unsigned int)ub << 16);
}

// ---- numpy-bit-exact pairwise sum of squares over 256 contiguous floats ----
__device__ __forceinline__ float np_sumsq_256(const float* __restrict__ a) {
    float half[2];
#pragma unroll
    for (int h = 0; h < 2; ++h) {
        const float* p = a + h * 128;
        float r[8];
#pragma unroll
        for (int j = 0; j < 8; ++j) r[j] = __fmul_rn(p[j], p[j]);
#pragma unroll
        for (int i = 8; i < 128; i += 8) {
#pragma unroll
            for (int j = 0; j < 8; ++j)
                r[j] = __fadd_rn(r[j], __fmul_rn(p[i + j], p[i + j]));
        }
        float ta = __fadd_rn(__fadd_rn(r[0], r[1]), __fadd_rn(r[2], r[3]));
        float tb = __fadd_rn(__fadd_rn(r[4], r[5]), __fadd_rn(r[6], r[7]));
        half[h] = __fadd_rn(ta, tb);
    }
    return __fadd_rn(half[0], half[1]);
}

__device__ __forceinline__ bool lex_lt(float s1, int k1, float s2, int k2) {
    return (s1 < s2) || (s1 == s2 && k1 < k2);
}

__device__ __forceinline__ void top2_merge(float& a1, int& ka1, float& a2, int& ka2,
                                           float b1, int kb1, float b2, int kb2) {
    if (lex_lt(b1, kb1, a1, ka1)) {
        float t1 = a1; int tk1 = ka1;
        a1 = b1; ka1 = kb1;
        if (lex_lt(b2, kb2, t1, tk1)) { a2 = b2; ka2 = kb2; }
        else                          { a2 = t1; ka2 = tk1; }
    } else {
        if (lex_lt(b1, kb1, a2, ka2)) { a2 = b1; ka2 = kb1; }
    }
}

// ---- kernel 1 (fused): blocks 0..1023 = z prep, 1024..1151 = emb prep ----
// z path additionally writes z_t (exact fp32 transposed z) when ws has room.
__global__ void __launch_bounds__(256)
prep_kernel(const float* __restrict__ z, const float* __restrict__ emb,
            f16* __restrict__ A, float* __restrict__ z2,
            float* __restrict__ e2, f16* __restrict__ e16,
            float* __restrict__ z_t) {
    const int t = threadIdx.x;
    if (blockIdx.x >= 1024) {
        // ---- emb path ----
        const int gid = (blockIdx.x - 1024) * 256 + t;    // 0..32767
        const int k = gid >> 5, seg = gid & 31;           // seg covers 8 c
        const float* src = emb + (size_t)k * CDIM + seg * 8;
        float4 v0 = *(const float4*)src;
        float4 v1 = *(const float4*)(src + 4);
        float s[8] = { v0.x, v0.y, v0.z, v0.w, v1.x, v1.y, v1.z, v1.w };
        f16 h[8], l[8];
#pragma unroll
        for (int j = 0; j < 8; ++j) {
            float sv = s[j] * 1024.0f;
            h[j] = (f16)sv;
            float r = __fsub_rn(sv, (float)h[j]);
            l[j] = (f16)r;
        }
        uint4 hv, lv;
        hv.x = pack_f16x2(h[0], h[1]); hv.y = pack_f16x2(h[2], h[3]);
        hv.z = pack_f16x2(h[4], h[5]); hv.w = pack_f16x2(h[6], h[7]);
        lv.x = pack_f16x2(l[0], l[1]); lv.y = pack_f16x2(l[2], l[3]);
        lv.z = pack_f16x2(l[4], l[5]); lv.w = pack_f16x2(l[6], l[7]);
        *(uint4*)(e16 + (size_t)k * 512 + seg * 8) = hv;
        *(uint4*)(e16 + (size_t)k * 512 + 256 + seg * 8) = lv;
        if (seg == 0) e2[k] = np_sumsq_256(emb + (size_t)k * CDIM);
        return;
    }
    // ---- z path ----
    __shared__ __align__(16) float z_lds[32 * 260];
    const int n0 = blockIdx.x * 32;
    const int b = n0 >> 10, hw0 = n0 & 1023;
    const float* zbase = z + (size_t)b * (CDIM * HW) + hw0;
#pragma unroll
    for (int p = 0; p < 8; ++p) {
        int id = p * 256 + t;
        int c = id >> 3;
        int m4 = id & 7;
        float4 v = *(const float4*)(zbase + (size_t)c * HW + m4 * 4);
        z_lds[(m4 * 4 + 0) * 260 + c] = v.x;
        z_lds[(m4 * 4 + 1) * 260 + c] = v.y;
        z_lds[(m4 * 4 + 2) * 260 + c] = v.z;
        z_lds[(m4 * 4 + 3) * 260 + c] = v.w;
    }
    __syncthreads();
    if (t < 32) z2[n0 + t] = np_sumsq_256(&z_lds[t * 260]);

    if (z_t) {
        // exact fp32 transposed copy: row n contiguous (coalesced float4 stores)
#pragma unroll
        for (int p = 0; p < 8; ++p) {
            int id = p * 256 + t;
            int m = id >> 6;             // row 0..31
            int c4 = (id & 63) * 4;      // 0..252
            float4 v = { z_lds[m * 260 + c4],     z_lds[m * 260 + c4 + 1],
                         z_lds[m * 260 + c4 + 2], z_lds[m * 260 + c4 + 3] };
            *(float4*)&z_t[(size_t)(n0 + m) * CDIM + c4] = v;
        }
    }

    const int lane = t & 63, wave = t >> 6;
    const int half = lane >> 5;       // 0 = hi, 1 = lo
    const int seg = lane & 31;        // 8 c per seg
#pragma unroll
    for (int rr = 0; rr < 8; ++rr) {
        const int m = wave * 8 + rr;
        const float* zr = &z_lds[m * 260 + seg * 8];
        f16 o[8];
#pragma unroll
        for (int j = 0; j < 8; ++j) {
            float sv = zr[j] * 16.0f;
            f16 hh = (f16)sv;
            if (half) {
                float r = __fsub_rn(sv, (float)hh);
                o[j] = (f16)r;
            } else {
                o[j] = hh;
            }
        }
        uint4 ov;
        ov.x = pack_f16x2(o[0], o[1]); ov.y = pack_f16x2(o[2], o[3]);
        ov.z = pack_f16x2(o[4], o[5]); ov.w = pack_f16x2(o[6], o[7]);
        *(uint4*)(A + (size_t)(n0 + m) * 512 + half * 256 + seg * 8) = ov;
    }
}

// ---- kernel 3: MFMA GEMM (codes-as-M, 32x32x16) + lane-local top2 ----
// WIDE-Z variant of the proven R4/R7 2-barrier dbuf loop (sync structure
// untouched): tile 128 codes x 256 z-rows, 8 waves (512 thr).
// Staged bytes per wave-MFMA: (8+8+16 KB)/64 = 0.5 vs R7's 24/32 = 0.75
// (code staging amortized over 2x z) -- this kernel is drain-stall-bound,
// so fewer staged bytes/FLOP is the lever. LDS 72.5 KB -> 2 blocks/CU =
// 16 waves/CU (vs 12). __launch_bounds__(512,4) caps VGPR at 128 (uses ~84,
// no spill -- R5 lesson). Per-wave inner structure IDENTICAL to R7:
// wc=(w&1)*64, wz=(w>>1)*64, acc[2][2], same MFMA order -> bit-identical acc.
// Grid 1024: Ntile=bid&127, Mtile=bid>>7 (8 same-z blocks == mod 8 -> same
// XCD; z set/XCD = 16 tiles x 256 KB = 4 MB = L2).
// Swizzle (rule 21, both sides): source granule (lane&3)^((row>>1)&3) with
// linear LDS dest; read granule (2*ks+hhalf)^((c31>>1)&3). Keys consistent:
// all staging-segment / fragment-row offsets are multiples of 16/32 so the
// (row>>1)&3 key reduces to the local forms used below.
// acc = dot * 2^14 -> 2*dot = acc * 2^-13.
__global__ void __launch_bounds__(512, 4)
gemm_argmin_kernel(const f16* __restrict__ A, const f16* __restrict__ B,
                   const float* __restrict__ z2, const float* __restrict__ e2,
                   float4* __restrict__ tile_red) {
    __shared__ __align__(16) f16 c1_lds[2][128 * 32];   // codes, aligned halves (16 KB)
    __shared__ __align__(16) f16 c2_lds[2][128 * 32];   // codes, swapped halves (16 KB)
    __shared__ __align__(16) f16 z_lds[2][256 * 32];    // z rows (32 KB)
    __shared__ __align__(16) float4 red_lds[2 * 256];   // 8 KB
    __shared__ float e2_lds[128];                       // 0.5 KB

    const int t = threadIdx.x;
    const int lane = t & 63, wave = t >> 6;     // wave 0..7
    const int Ntile = blockIdx.x & 127;         // z-row tile (128 total, 256 rows each)
    const int Mtile = blockIdx.x >> 7;          // code tile (8 total)
    const int wc = (wave & 1) * 64;             // code offset in tile
    const int wz = (wave >> 1) * 64;            // zrow offset in tile (4 quarters)
    const int c31 = lane & 31, hhalf = lane >> 5;
    const int gsw = (c31 >> 1) & 3;             // read-side bank swizzle key

    if (t < 128) e2_lds[t] = e2[Mtile * 128 + t];

    // staging: per chunk 32 segments of 1 KB (c1: 8, c2: 8, z: 16).
    // wave w stages c1 seg w, c2 seg w, z segs 2w and 2w+1.
    const char* Cbase = (const char*)(B + (size_t)Mtile * 128 * 512);  // codebook f16
    const char* Zbase = (const char*)(A + (size_t)Ntile * 256 * 512);  // z f16
    const int lrow = lane >> 2;
    const int lsw = ((lane & 3) ^ ((lrow >> 1) & 3)) * 16;
    const char* cg  = Cbase + (size_t)(wave * 16 + lrow) * 1024 + lsw;
    const char* zg0 = Zbase + (size_t)((2 * wave) * 16 + lrow) * 1024 + lsw;
    const char* zg1 = Zbase + (size_t)((2 * wave + 1) * 16 + lrow) * 1024 + lsw;
    const int woffc  = wave * 512;              // f16 offset of wave's c segment
    const int woffz0 = (2 * wave) * 512;
    const int woffz1 = (2 * wave + 1) * 512;

    // per-lane ds_read bases (f16 index): row*32, plus swizzled granule per ks
    int crow32[2], zrow32[2], g8[2];
#pragma unroll
    for (int i = 0; i < 2; ++i) crow32[i] = (wc + i * 32 + c31) * 32;
#pragma unroll
    for (int j = 0; j < 2; ++j) zrow32[j] = (wz + j * 32 + c31) * 32;
#pragma unroll
    for (int ks = 0; ks < 2; ++ks) g8[ks] = ((2 * ks + hhalf) ^ gsw) * 8;

    f32x16 acc[2][2] = {};

    // preload chunk 0 into buf 0 (4 glds per thread-wave-slot)
    glds16(cg,        &c1_lds[0][woffc]);
    glds16(cg + 512,  &c2_lds[0][woffc]);
    glds16(zg0,       &z_lds[0][woffz0]);
    glds16(zg1,       &z_lds[0][woffz1]);
    __syncthreads();   // vmcnt(0) drain: chunk 0 resident

    for (int kk = 0; kk < 16; ++kk) {
        const int buf = kk & 1;
        if (kk < 15) {
            const int nb = buf ^ 1;
            const int ko = (kk + 1) * 64;            // byte offset in 1024-B row
            const int ko2 = (ko + 512) & 1023;
            glds16(cg + ko,   &c1_lds[nb][woffc]);
            glds16(cg + ko2,  &c2_lds[nb][woffc]);
            glds16(zg0 + ko,  &z_lds[nb][woffz0]);
            glds16(zg1 + ko,  &z_lds[nb][woffz1]);
        }

#pragma unroll
        for (int ks = 0; ks < 2; ++ks) {
            f16x8 zf[2], cf1[2], cf2[2];
#pragma unroll
            for (int j = 0; j < 2; ++j)
                zf[j] = *(const f16x8*)&z_lds[buf][zrow32[j] + g8[ks]];
#pragma unroll
            for (int i = 0; i < 2; ++i) {
                cf1[i] = *(const f16x8*)&c1_lds[buf][crow32[i] + g8[ks]];
                cf2[i] = *(const f16x8*)&c2_lds[buf][crow32[i] + g8[ks]];
            }
#pragma unroll
            for (int i = 0; i < 2; ++i)
#pragma unroll
                for (int j = 0; j < 2; ++j) {
                    acc[i][j] = __builtin_amdgcn_mfma_f32_32x32x16_f16(cf1[i], zf[j], acc[i][j], 0, 0, 0);
                    acc[i][j] = __builtin_amdgcn_mfma_f32_32x32x16_f16(cf2[i], zf[j], acc[i][j], 0, 0, 0);
                }
        }
        __syncthreads();   // drains vmcnt: chunk kk+1 resident; buf^1 safe next iter
    }

    // ---- epilogue: d = fl(fl(z2+e2) - fl(acc*2^-13)); lane-local top2 over 32 codes ----
#pragma unroll
    for (int j = 0; j < 2; ++j) {
        const float z2v = z2[Ntile * 256 + wz + j * 32 + c31];
        float s1 = FLT_BIG, s2 = FLT_BIG;
        int k1 = KCODES, k2 = KCODES;
#pragma unroll
        for (int i = 0; i < 2; ++i) {
            const int cbase = wc + i * 32 + 4 * hhalf;
#pragma unroll
            for (int r = 0; r < 16; ++r) {
                const int clocal = cbase + (r & 3) + 8 * (r >> 2);
                const float e2r = e2_lds[clocal];
                const float d = __fsub_rn(__fadd_rn(z2v, e2r),
                                          __fmul_rn(acc[i][j][r], 1.220703125e-4f));
                const int kc = Mtile * 128 + clocal;
                if (lex_lt(d, kc, s1, k1)) { s2 = s1; k2 = k1; s1 = d; k1 = kc; }
                else if (lex_lt(d, kc, s2, k2)) { s2 = d; k2 = kc; }
            }
        }
        // partner merge: lanes l and l^32 share the same z-row, complementary codes
        float b1 = __shfl_xor(s1, 32); int kb1 = __shfl_xor(k1, 32);
        float b2 = __shfl_xor(s2, 32); int kb2 = __shfl_xor(k2, 32);
        top2_merge(s1, k1, s2, k2, b1, kb1, b2, kb2);
        if (hhalf == 0) {
            float4 st;
            st.x = s1; st.y = __int_as_float(k1);
            st.z = s2; st.w = __int_as_float(k2);
            red_lds[(wave & 1) * 256 + wz + j * 32 + c31] = st;
        }
    }
    __syncthreads();
    if (t < 256) {
        float4 a = red_lds[t];
        float4 b = red_lds[256 + t];
        float a1 = a.x, a2 = a.z; int ka1 = __float_as_int(a.y), ka2 = __float_as_int(a.w);
        top2_merge(a1, ka1, a2, ka2, b.x, __float_as_int(b.y), b.z, __float_as_int(b.w));
        float4 o;
        o.x = a1; o.y = __int_as_float(ka1); o.z = a2; o.w = __int_as_float(ka2);
        tile_red[(size_t)(Ntile * 256 + t) * 8 + Mtile] = o;
    }
}

// ---- kernel 4: candidate reduce + exact fp32 rescore, 4 lanes per row ----
// (R8-verified: 4 lanes/row TLP + z_t coalesced reads; bit-identical argmin.)
__global__ void __launch_bounds__(256)
rescore_kernel(const float* __restrict__ z, const float* __restrict__ emb,
               const float* __restrict__ z2, const float* __restrict__ e2,
               const float4* __restrict__ tile_red, const float* __restrict__ z_t,
               float* __restrict__ out_idx_f, int* __restrict__ ws_idx) {
    const int gid = blockIdx.x * 256 + threadIdx.x;
    const int n = gid >> 2, q = gid & 3;

    float s[4]; int k[4];
    const float4 v0 = tile_red[(size_t)n * 8 + q * 2];
    const float4 v1 = tile_red[(size_t)n * 8 + q * 2 + 1];
    s[0] = v0.x; k[0] = __float_as_int(v0.y);
    s[1] = v0.z; k[1] = __float_as_int(v0.w);
    s[2] = v1.x; k[2] = __float_as_int(v1.y);
    s[3] = v1.z; k[3] = __float_as_int(v1.w);

    float s1 = FLT_BIG; int k1 = KCODES;
#pragma unroll
    for (int i = 0; i < 4; ++i)
        if (lex_lt(s[i], k[i], s1, k1)) { s1 = s[i]; k1 = k[i]; }
    // merge global top1 across the 4-lane group (masks 1,2 stay in-group)
#pragma unroll
    for (int m = 1; m <= 2; m <<= 1) {
        float bs = __shfl_xor(s1, m); int bk2 = __shfl_xor(k1, m);
        if (lex_lt(bs, bk2, s1, k1)) { s1 = bs; k1 = bk2; }
    }
    const float thr = s1 + 1.0e-4f;
    int cnt = 0;
#pragma unroll
    for (int i = 0; i < 4; ++i) cnt += (s[i] <= thr) ? 1 : 0;
    cnt += __shfl_xor(cnt, 1);
    cnt += __shfl_xor(cnt, 2);

    int bk = k1;
    if (cnt > 1) {
        int kk[4];
#pragma unroll
        for (int i = 0; i < 4; ++i) kk[i] = (s[i] <= thr) ? k[i] : k1;
        float accs[4] = { 0.f, 0.f, 0.f, 0.f };
        if (z_t) {
            const float* zr = z_t + (size_t)n * CDIM;
            for (int c0 = 0; c0 < 256; c0 += 4) {
                const float4 zv = *(const float4*)&zr[c0];
#pragma unroll
                for (int j = 0; j < 4; ++j) {
                    float4 ev = *(const float4*)&emb[(size_t)kk[j] * CDIM + c0];
                    accs[j] = fmaf(zv.x, ev.x, accs[j]);
                    accs[j] = fmaf(zv.y, ev.y, accs[j]);
                    accs[j] = fmaf(zv.z, ev.z, accs[j]);
                    accs[j] = fmaf(zv.w, ev.w, accs[j]);
                }
            }
        } else {
            const float* zb = z + (size_t)(n >> 10) * (CDIM * HW) + (n & 1023);
            for (int c0 = 0; c0 < 256; c0 += 4) {
                float zc0 = zb[(size_t)(c0 + 0) * HW];
                float zc1 = zb[(size_t)(c0 + 1) * HW];
                float zc2 = zb[(size_t)(c0 + 2) * HW];
                float zc3 = zb[(size_t)(c0 + 3) * HW];
#pragma unroll
                for (int j = 0; j < 4; ++j) {
                    float4 ev = *(const float4*)&emb[(size_t)kk[j] * CDIM + c0];
                    accs[j] = fmaf(zc0, ev.x, accs[j]);
                    accs[j] = fmaf(zc1, ev.y, accs[j]);
                    accs[j] = fmaf(zc2, ev.z, accs[j]);
                    accs[j] = fmaf(zc3, ev.w, accs[j]);
                }
            }
        }
        float bd = FLT_BIG; bk = KCODES;
        const float z2n = z2[n];
#pragma unroll
        for (int j = 0; j < 4; ++j) {
            float d = __fsub_rn(__fadd_rn(z2n, e2[kk[j]]), accs[j] + accs[j]);
            if (lex_lt(d, kk[j], bd, bk)) { bd = d; bk = kk[j]; }
        }
        // merge exact best across the 4-lane group
#pragma unroll
        for (int m = 1; m <= 2; m <<= 1) {
            float bs = __shfl_xor(bd, m); int bb = __shfl_xor(bk, m);
            if (lex_lt(bs, bb, bd, bk)) { bd = bs; bk = bb; }
        }
    }
    if (q == 0) {
        out_idx_f[n] = (float)bk;
        ws_idx[n] = bk;
    }
}

// ---- kernel 5: gather z_q, write z_q_st, partial loss sums ----
__global__ void __launch_bounds__(256)
gather_kernel(const float* __restrict__ z, const float* __restrict__ emb,
              const int* __restrict__ ws_idx, float* __restrict__ out_zq,
              float* __restrict__ partials) {
    const int t = threadIdx.x;
    const int b = blockIdx.x >> 5;
    const int cg = blockIdx.x & 31;
    const int hw4 = t * 4;

    const int4 iv = *(const int4*)&ws_idx[b * HW + hw4];
    const float* zb = z + (size_t)b * (CDIM * HW) + hw4;
    float* ob = out_zq + (size_t)b * (CDIM * HW) + hw4;
    const float* e0p = emb + (size_t)iv.x * CDIM;
    const float* e1p = emb + (size_t)iv.y * CDIM;
    const float* e2p = emb + (size_t)iv.z * CDIM;
    const float* e3p = emb + (size_t)iv.w * CDIM;

    float lsum = 0.f;
#pragma unroll
    for (int c = cg * 8; c < cg * 8 + 8; ++c) {
        float4 zv = *(const float4*)&zb[(size_t)c * HW];
        float d0 = e0p[c] - zv.x;
        float d1 = e1p[c] - zv.y;
        float d2 = e2p[c] - zv.z;
        float d3 = e3p[c] - zv.w;
        float4 ov = { zv.x + d0, zv.y + d1, zv.z + d2, zv.w + d3 };
        *(float4*)&ob[(size_t)c * HW] = ov;
        lsum = fmaf(d0, d0, lsum);
        lsum = fmaf(d1, d1, lsum);
        lsum = fmaf(d2, d2, lsum);
        lsum = fmaf(d3, d3, lsum);
    }
#pragma unroll
    for (int off = 32; off > 0; off >>= 1) lsum += __shfl_down(lsum, off);
    __shared__ float wsum[4];
    if ((t & 63) == 0) wsum[t >> 6] = lsum;
    __syncthreads();
    if (t == 0) partials[blockIdx.x] = (wsum[0] + wsum[1]) + (wsum[2] + wsum[3]);
}

// ---- kernel 6: finalize loss = 1.25 * mean(diff^2) over 1024 partials ----
__global__ void loss_kernel(const float* __restrict__ partials, float* __restrict__ out_loss) {
    const int t = threadIdx.x;
    float4 v4 = *(const float4*)&partials[t * 4];
    float v = (v4.x + v4.y) + (v4.z + v4.w);
#pragma unroll
    for (int off = 32; off > 0; off >>= 1) v += __shfl_down(v, off);
    __shared__ float wsum[4];
    if ((t & 63) == 0) wsum[t >> 6] = v;
    __syncthreads();
    if (t == 0) {
        float total = (wsum[0] + wsum[1]) + (wsum[2] + wsum[3]);
        out_loss[0] = 1.25f * total / 8388608.0f;
    }
}

extern "C" void kernel_launch(void* const* d_in, const int* in_sizes, int n_in,
                              void* d_out, int out_size, void* d_ws, size_t ws_size,
                              hipStream_t stream) {
    const float* z   = (const float*)d_in[0];
    const float* emb = (const float*)d_in[1];
    float* out = (float*)d_out;

    // A (fp16 [32768][512] = 32 MB) lives in the zq region of d_out; gather overwrites it last.
    f16* A = (f16*)d_out;

    char* w = (char*)d_ws;
    float*  e2       = (float*)(w + 0);            // 4 KB
    float*  z2       = (float*)(w + 4096);         // 128 KB
    f16*    e16      = (f16*)(w + 135168);         // 1 MB
    float4* tile_red = (float4*)(w + 1183744);     // 4 MB
    int*    ws_idx   = (int*)(w + 5378048);        // 128 KB
    float*  partials = (float*)(w + 5509120);      // 4 KB

    // z_t: exact fp32 transposed z for coalesced rescore (guarded by ws_size)
    const size_t zt_need = ZT_OFF + (size_t)NROWS * CDIM * sizeof(float);
    float* z_t = (ws_size >= zt_need) ? (float*)(w + ZT_OFF) : nullptr;

    hipLaunchKernelGGL(prep_kernel, dim3(1152), dim3(256), 0, stream,
                       z, emb, A, z2, e2, e16, z_t);
    hipLaunchKernelGGL(gemm_argmin_kernel, dim3(1024), dim3(512), 0, stream,
                       A, e16, z2, e2, tile_red);
    hipLaunchKernelGGL(rescore_kernel, dim3(512), dim3(256), 0, stream,
                       z, emb, z2, e2, tile_red, z_t, out + IDX_OFF, ws_idx);
    hipLaunchKernelGGL(gather_kernel, dim3(1024), dim3(256), 0, stream,
                       z, emb, ws_idx, out, partials);
    hipLaunchKernelGGL(loss_kernel, dim3(1), dim3(256), 0, stream,
                       partials, out + LOSS_OFF);
}

// Round 10
// 210.158 us; speedup vs baseline: 1.2873x; 1.2873x over previous
//
#include <hip/hip_runtime.h>

#define CDIM 256
#define HW 1024            // 32*32
#define NROWS 32768        // 32*1024
#define KCODES 1024
#define ZQ_ELEMS 8388608   // 32*256*1024
#define IDX_OFF ZQ_ELEMS
#define LOSS_OFF (ZQ_ELEMS + NROWS)
#define FLT_BIG 3.402823466e+38f
#define ZT_OFF 5513232ull  // 16B-aligned; z_t fp32 [32768][256] = 32 MB (ws-guarded)

typedef _Float16 f16;
typedef _Float16 f16x8 __attribute__((ext_vector_type(8)));
typedef float f32x4 __attribute__((ext_vector_type(4)));
typedef float f32x16 __attribute__((ext_vector_type(16)));

// async global->LDS, 16 B per lane; LDS dest = wave-uniform base + lane*16
__device__ __forceinline__ void glds16(const void* g, void* l) {
    __builtin_amdgcn_global_load_lds(
        (const __attribute__((address_space(1))) unsigned int*)g,
        (__attribute__((address_space(3))) unsigned int*)l,
        16, 0, 0);
}

__device__ __forceinline__ unsigned int pack_f16x2(f16 a, f16 b) {
    unsigned short ua = *(unsigned short*)&a, ub = *(unsigned short*)&b;
    return (unsigned int)ua | ((unsigned int)ub << 16);
}

// ---- numpy-bit-exact pairwise sum of squares over 256 contiguous floats ----
__device__ __forceinline__ float np_sumsq_256(const float* __restrict__ a) {
    float half[2];
#pragma unroll
    for (int h = 0; h < 2; ++h) {
        const float* p = a + h * 128;
        float r[8];
#pragma unroll
        for (int j = 0; j < 8; ++j) r[j] = __fmul_rn(p[j], p[j]);
#pragma unroll
        for (int i = 8; i < 128; i += 8) {
#pragma unroll
            for (int j = 0; j < 8; ++j)
                r[j] = __fadd_rn(r[j], __fmul_rn(p[i + j], p[i + j]));
        }
        float ta = __fadd_rn(__fadd_rn(r[0], r[1]), __fadd_rn(r[2], r[3]));
        float tb = __fadd_rn(__fadd_rn(r[4], r[5]), __fadd_rn(r[6], r[7]));
        half[h] = __fadd_rn(ta, tb);
    }
    return __fadd_rn(half[0], half[1]);
}

__device__ __forceinline__ bool lex_lt(float s1, int k1, float s2, int k2) {
    return (s1 < s2) || (s1 == s2 && k1 < k2);
}

__device__ __forceinline__ void top2_merge(float& a1, int& ka1, float& a2, int& ka2,
                                           float b1, int kb1, float b2, int kb2) {
    if (lex_lt(b1, kb1, a1, ka1)) {
        float t1 = a1; int tk1 = ka1;
        a1 = b1; ka1 = kb1;
        if (lex_lt(b2, kb2, t1, tk1)) { a2 = b2; ka2 = kb2; }
        else                          { a2 = t1; ka2 = tk1; }
    } else {
        if (lex_lt(b1, kb1, a2, ka2)) { a2 = b1; ka2 = kb1; }
    }
}

// ---- kernel 1 (fused): blocks 0..1023 = z prep, 1024..1151 = emb prep ----
// z path additionally writes z_t (exact fp32 transposed z) when ws has room.
__global__ void __launch_bounds__(256)
prep_kernel(const float* __restrict__ z, const float* __restrict__ emb,
            f16* __restrict__ A, float* __restrict__ z2,
            float* __restrict__ e2, f16* __restrict__ e16,
            float* __restrict__ z_t) {
    const int t = threadIdx.x;
    if (blockIdx.x >= 1024) {
        // ---- emb path ----
        const int gid = (blockIdx.x - 1024) * 256 + t;    // 0..32767
        const int k = gid >> 5, seg = gid & 31;           // seg covers 8 c
        const float* src = emb + (size_t)k * CDIM + seg * 8;
        float4 v0 = *(const float4*)src;
        float4 v1 = *(const float4*)(src + 4);
        float s[8] = { v0.x, v0.y, v0.z, v0.w, v1.x, v1.y, v1.z, v1.w };
        f16 h[8], l[8];
#pragma unroll
        for (int j = 0; j < 8; ++j) {
            float sv = s[j] * 1024.0f;
            h[j] = (f16)sv;
            float r = __fsub_rn(sv, (float)h[j]);
            l[j] = (f16)r;
        }
        uint4 hv, lv;
        hv.x = pack_f16x2(h[0], h[1]); hv.y = pack_f16x2(h[2], h[3]);
        hv.z = pack_f16x2(h[4], h[5]); hv.w = pack_f16x2(h[6], h[7]);
        lv.x = pack_f16x2(l[0], l[1]); lv.y = pack_f16x2(l[2], l[3]);
        lv.z = pack_f16x2(l[4], l[5]); lv.w = pack_f16x2(l[6], l[7]);
        *(uint4*)(e16 + (size_t)k * 512 + seg * 8) = hv;
        *(uint4*)(e16 + (size_t)k * 512 + 256 + seg * 8) = lv;
        if (seg == 0) e2[k] = np_sumsq_256(emb + (size_t)k * CDIM);
        return;
    }
    // ---- z path ----
    __shared__ __align__(16) float z_lds[32 * 260];
    const int n0 = blockIdx.x * 32;
    const int b = n0 >> 10, hw0 = n0 & 1023;
    const float* zbase = z + (size_t)b * (CDIM * HW) + hw0;
#pragma unroll
    for (int p = 0; p < 8; ++p) {
        int id = p * 256 + t;
        int c = id >> 3;
        int m4 = id & 7;
        float4 v = *(const float4*)(zbase + (size_t)c * HW + m4 * 4);
        z_lds[(m4 * 4 + 0) * 260 + c] = v.x;
        z_lds[(m4 * 4 + 1) * 260 + c] = v.y;
        z_lds[(m4 * 4 + 2) * 260 + c] = v.z;
        z_lds[(m4 * 4 + 3) * 260 + c] = v.w;
    }
    __syncthreads();
    if (t < 32) z2[n0 + t] = np_sumsq_256(&z_lds[t * 260]);

    if (z_t) {
        // exact fp32 transposed copy: row n contiguous (coalesced float4 stores)
#pragma unroll
        for (int p = 0; p < 8; ++p) {
            int id = p * 256 + t;
            int m = id >> 6;             // row 0..31
            int c4 = (id & 63) * 4;      // 0..252
            float4 v = { z_lds[m * 260 + c4],     z_lds[m * 260 + c4 + 1],
                         z_lds[m * 260 + c4 + 2], z_lds[m * 260 + c4 + 3] };
            *(float4*)&z_t[(size_t)(n0 + m) * CDIM + c4] = v;
        }
    }

    const int lane = t & 63, wave = t >> 6;
    const int half = lane >> 5;       // 0 = hi, 1 = lo
    const int seg = lane & 31;        // 8 c per seg
#pragma unroll
    for (int rr = 0; rr < 8; ++rr) {
        const int m = wave * 8 + rr;
        const float* zr = &z_lds[m * 260 + seg * 8];
        f16 o[8];
#pragma unroll
        for (int j = 0; j < 8; ++j) {
            float sv = zr[j] * 16.0f;
            f16 hh = (f16)sv;
            if (half) {
                float r = __fsub_rn(sv, (float)hh);
                o[j] = (f16)r;
            } else {
                o[j] = hh;
            }
        }
        uint4 ov;
        ov.x = pack_f16x2(o[0], o[1]); ov.y = pack_f16x2(o[2], o[3]);
        ov.z = pack_f16x2(o[4], o[5]); ov.w = pack_f16x2(o[6], o[7]);
        *(uint4*)(A + (size_t)(n0 + m) * 512 + half * 256 + seg * 8) = ov;
    }
}

// ---- kernel 3: MFMA GEMM (codes-as-M, 32x32x16) + lane-local top2 ----
// WIDE-Z tile: 128 codes x 256 z-rows, 8 waves (512 thr), R4-proven
// 2-barrier BK=32 dbuf loop. Staged bytes/wave-MFMA = 0.5 KB (vs 0.75 at
// 128x128). LDS 72.5 KB -> 2 blocks/CU = 16 waves/CU.
// VGPR-CAP RULE (measured): hipcc cap ~= 256 / launch_bounds_arg2:
//   (256,3)->84 ok; (256,4)->64 SPILL (R5); (512,4)->64 SPILL (R9, 152us
//   even WITH 250MB scratch traffic). This kernel needs ~84 VGPR ->
//   __launch_bounds__(512, 2) (cap ~128). Occupancy is LDS-bound at
//   2 blocks/CU either way, so the cap relaxation costs nothing.
// Grid 1024: Ntile=bid&127, Mtile=bid>>7 (8 same-z blocks == mod 8 -> same
// XCD; z set/XCD = 16 tiles x 256 KB = 4 MB = L2).
// Swizzle (rule 21, both sides) and MFMA order identical to R7 ->
// bit-identical acc; epilogue/rescore semantics unchanged.
// acc = dot * 2^14 -> 2*dot = acc * 2^-13.
__global__ void __launch_bounds__(512, 2)
gemm_argmin_kernel(const f16* __restrict__ A, const f16* __restrict__ B,
                   const float* __restrict__ z2, const float* __restrict__ e2,
                   float4* __restrict__ tile_red) {
    __shared__ __align__(16) f16 c1_lds[2][128 * 32];   // codes, aligned halves (16 KB)
    __shared__ __align__(16) f16 c2_lds[2][128 * 32];   // codes, swapped halves (16 KB)
    __shared__ __align__(16) f16 z_lds[2][256 * 32];    // z rows (32 KB)
    __shared__ __align__(16) float4 red_lds[2 * 256];   // 8 KB
    __shared__ float e2_lds[128];                       // 0.5 KB

    const int t = threadIdx.x;
    const int lane = t & 63, wave = t >> 6;     // wave 0..7
    const int Ntile = blockIdx.x & 127;         // z-row tile (128 total, 256 rows each)
    const int Mtile = blockIdx.x >> 7;          // code tile (8 total)
    const int wc = (wave & 1) * 64;             // code offset in tile
    const int wz = (wave >> 1) * 64;            // zrow offset in tile (4 quarters)
    const int c31 = lane & 31, hhalf = lane >> 5;
    const int gsw = (c31 >> 1) & 3;             // read-side bank swizzle key

    if (t < 128) e2_lds[t] = e2[Mtile * 128 + t];

    // staging: per chunk 32 segments of 1 KB (c1: 8, c2: 8, z: 16).
    // wave w stages c1 seg w, c2 seg w, z segs 2w and 2w+1.
    const char* Cbase = (const char*)(B + (size_t)Mtile * 128 * 512);  // codebook f16
    const char* Zbase = (const char*)(A + (size_t)Ntile * 256 * 512);  // z f16
    const int lrow = lane >> 2;
    const int lsw = ((lane & 3) ^ ((lrow >> 1) & 3)) * 16;
    const char* cg  = Cbase + (size_t)(wave * 16 + lrow) * 1024 + lsw;
    const char* zg0 = Zbase + (size_t)((2 * wave) * 16 + lrow) * 1024 + lsw;
    const char* zg1 = Zbase + (size_t)((2 * wave + 1) * 16 + lrow) * 1024 + lsw;
    const int woffc  = wave * 512;              // f16 offset of wave's c segment
    const int woffz0 = (2 * wave) * 512;
    const int woffz1 = (2 * wave + 1) * 512;

    // per-lane ds_read bases (f16 index): row*32, plus swizzled granule per ks
    int crow32[2], zrow32[2], g8[2];
#pragma unroll
    for (int i = 0; i < 2; ++i) crow32[i] = (wc + i * 32 + c31) * 32;
#pragma unroll
    for (int j = 0; j < 2; ++j) zrow32[j] = (wz + j * 32 + c31) * 32;
#pragma unroll
    for (int ks = 0; ks < 2; ++ks) g8[ks] = ((2 * ks + hhalf) ^ gsw) * 8;

    f32x16 acc[2][2] = {};

    // preload chunk 0 into buf 0 (4 glds per thread-wave-slot)
    glds16(cg,        &c1_lds[0][woffc]);
    glds16(cg + 512,  &c2_lds[0][woffc]);
    glds16(zg0,       &z_lds[0][woffz0]);
    glds16(zg1,       &z_lds[0][woffz1]);
    __syncthreads();   // vmcnt(0) drain: chunk 0 resident

    for (int kk = 0; kk < 16; ++kk) {
        const int buf = kk & 1;
        if (kk < 15) {
            const int nb = buf ^ 1;
            const int ko = (kk + 1) * 64;            // byte offset in 1024-B row
            const int ko2 = (ko + 512) & 1023;
            glds16(cg + ko,   &c1_lds[nb][woffc]);
            glds16(cg + ko2,  &c2_lds[nb][woffc]);
            glds16(zg0 + ko,  &z_lds[nb][woffz0]);
            glds16(zg1 + ko,  &z_lds[nb][woffz1]);
        }

#pragma unroll
        for (int ks = 0; ks < 2; ++ks) {
            f16x8 zf[2], cf1[2], cf2[2];
#pragma unroll
            for (int j = 0; j < 2; ++j)
                zf[j] = *(const f16x8*)&z_lds[buf][zrow32[j] + g8[ks]];
#pragma unroll
            for (int i = 0; i < 2; ++i) {
                cf1[i] = *(const f16x8*)&c1_lds[buf][crow32[i] + g8[ks]];
                cf2[i] = *(const f16x8*)&c2_lds[buf][crow32[i] + g8[ks]];
            }
#pragma unroll
            for (int i = 0; i < 2; ++i)
#pragma unroll
                for (int j = 0; j < 2; ++j) {
                    acc[i][j] = __builtin_amdgcn_mfma_f32_32x32x16_f16(cf1[i], zf[j], acc[i][j], 0, 0, 0);
                    acc[i][j] = __builtin_amdgcn_mfma_f32_32x32x16_f16(cf2[i], zf[j], acc[i][j], 0, 0, 0);
                }
        }
        __syncthreads();   // drains vmcnt: chunk kk+1 resident; buf^1 safe next iter
    }

    // ---- epilogue: d = fl(fl(z2+e2) - fl(acc*2^-13)); lane-local top2 over 32 codes ----
#pragma unroll
    for (int j = 0; j < 2; ++j) {
        const float z2v = z2[Ntile * 256 + wz + j * 32 + c31];
        float s1 = FLT_BIG, s2 = FLT_BIG;
        int k1 = KCODES, k2 = KCODES;
#pragma unroll
        for (int i = 0; i < 2; ++i) {
            const int cbase = wc + i * 32 + 4 * hhalf;
#pragma unroll
            for (int r = 0; r < 16; ++r) {
                const int clocal = cbase + (r & 3) + 8 * (r >> 2);
                const float e2r = e2_lds[clocal];
                const float d = __fsub_rn(__fadd_rn(z2v, e2r),
                                          __fmul_rn(acc[i][j][r], 1.220703125e-4f));
                const int kc = Mtile * 128 + clocal;
                if (lex_lt(d, kc, s1, k1)) { s2 = s1; k2 = k1; s1 = d; k1 = kc; }
                else if (lex_lt(d, kc, s2, k2)) { s2 = d; k2 = kc; }
            }
        }
        // partner merge: lanes l and l^32 share the same z-row, complementary codes
        float b1 = __shfl_xor(s1, 32); int kb1 = __shfl_xor(k1, 32);
        float b2 = __shfl_xor(s2, 32); int kb2 = __shfl_xor(k2, 32);
        top2_merge(s1, k1, s2, k2, b1, kb1, b2, kb2);
        if (hhalf == 0) {
            float4 st;
            st.x = s1; st.y = __int_as_float(k1);
            st.z = s2; st.w = __int_as_float(k2);
            red_lds[(wave & 1) * 256 + wz + j * 32 + c31] = st;
        }
    }
    __syncthreads();
    if (t < 256) {
        float4 a = red_lds[t];
        float4 b = red_lds[256 + t];
        float a1 = a.x, a2 = a.z; int ka1 = __float_as_int(a.y), ka2 = __float_as_int(a.w);
        top2_merge(a1, ka1, a2, ka2, b.x, __float_as_int(b.y), b.z, __float_as_int(b.w));
        float4 o;
        o.x = a1; o.y = __int_as_float(ka1); o.z = a2; o.w = __int_as_float(ka2);
        tile_red[(size_t)(Ntile * 256 + t) * 8 + Mtile] = o;
    }
}

// ---- kernel 4: candidate reduce + exact fp32 rescore, 4 lanes per row ----
// (R8-verified: 4 lanes/row TLP + z_t coalesced reads; bit-identical argmin.)
__global__ void __launch_bounds__(256)
rescore_kernel(const float* __restrict__ z, const float* __restrict__ emb,
               const float* __restrict__ z2, const float* __restrict__ e2,
               const float4* __restrict__ tile_red, const float* __restrict__ z_t,
               float* __restrict__ out_idx_f, int* __restrict__ ws_idx) {
    const int gid = blockIdx.x * 256 + threadIdx.x;
    const int n = gid >> 2, q = gid & 3;

    float s[4]; int k[4];
    const float4 v0 = tile_red[(size_t)n * 8 + q * 2];
    const float4 v1 = tile_red[(size_t)n * 8 + q * 2 + 1];
    s[0] = v0.x; k[0] = __float_as_int(v0.y);
    s[1] = v0.z; k[1] = __float_as_int(v0.w);
    s[2] = v1.x; k[2] = __float_as_int(v1.y);
    s[3] = v1.z; k[3] = __float_as_int(v1.w);

    float s1 = FLT_BIG; int k1 = KCODES;
#pragma unroll
    for (int i = 0; i < 4; ++i)
        if (lex_lt(s[i], k[i], s1, k1)) { s1 = s[i]; k1 = k[i]; }
    // merge global top1 across the 4-lane group (masks 1,2 stay in-group)
#pragma unroll
    for (int m = 1; m <= 2; m <<= 1) {
        float bs = __shfl_xor(s1, m); int bk2 = __shfl_xor(k1, m);
        if (lex_lt(bs, bk2, s1, k1)) { s1 = bs; k1 = bk2; }
    }
    const float thr = s1 + 1.0e-4f;
    int cnt = 0;
#pragma unroll
    for (int i = 0; i < 4; ++i) cnt += (s[i] <= thr) ? 1 : 0;
    cnt += __shfl_xor(cnt, 1);
    cnt += __shfl_xor(cnt, 2);

    int bk = k1;
    if (cnt > 1) {
        int kk[4];
#pragma unroll
        for (int i = 0; i < 4; ++i) kk[i] = (s[i] <= thr) ? k[i] : k1;
        float accs[4] = { 0.f, 0.f, 0.f, 0.f };
        if (z_t) {
            const float* zr = z_t + (size_t)n * CDIM;
            for (int c0 = 0; c0 < 256; c0 += 4) {
                const float4 zv = *(const float4*)&zr[c0];
#pragma unroll
                for (int j = 0; j < 4; ++j) {
                    float4 ev = *(const float4*)&emb[(size_t)kk[j] * CDIM + c0];
                    accs[j] = fmaf(zv.x, ev.x, accs[j]);
                    accs[j] = fmaf(zv.y, ev.y, accs[j]);
                    accs[j] = fmaf(zv.z, ev.z, accs[j]);
                    accs[j] = fmaf(zv.w, ev.w, accs[j]);
                }
            }
        } else {
            const float* zb = z + (size_t)(n >> 10) * (CDIM * HW) + (n & 1023);
            for (int c0 = 0; c0 < 256; c0 += 4) {
                float zc0 = zb[(size_t)(c0 + 0) * HW];
                float zc1 = zb[(size_t)(c0 + 1) * HW];
                float zc2 = zb[(size_t)(c0 + 2) * HW];
                float zc3 = zb[(size_t)(c0 + 3) * HW];
#pragma unroll
                for (int j = 0; j < 4; ++j) {
                    float4 ev = *(const float4*)&emb[(size_t)kk[j] * CDIM + c0];
                    accs[j] = fmaf(zc0, ev.x, accs[j]);
                    accs[j] = fmaf(zc1, ev.y, accs[j]);
                    accs[j] = fmaf(zc2, ev.z, accs[j]);
                    accs[j] = fmaf(zc3, ev.w, accs[j]);
                }
            }
        }
        float bd = FLT_BIG; bk = KCODES;
        const float z2n = z2[n];
#pragma unroll
        for (int j = 0; j < 4; ++j) {
            float d = __fsub_rn(__fadd_rn(z2n, e2[kk[j]]), accs[j] + accs[j]);
            if (lex_lt(d, kk[j], bd, bk)) { bd = d; bk = kk[j]; }
        }
        // merge exact best across the 4-lane group
#pragma unroll
        for (int m = 1; m <= 2; m <<= 1) {
            float bs = __shfl_xor(bd, m); int bb = __shfl_xor(bk, m);
            if (lex_lt(bs, bb, bd, bk)) { bd = bs; bk = bb; }
        }
    }
    if (q == 0) {
        out_idx_f[n] = (float)bk;
        ws_idx[n] = bk;
    }
}

// ---- kernel 5: gather z_q, write z_q_st, partial loss sums ----
__global__ void __launch_bounds__(256)
gather_kernel(const float* __restrict__ z, const float* __restrict__ emb,
              const int* __restrict__ ws_idx, float* __restrict__ out_zq,
              float* __restrict__ partials) {
    const int t = threadIdx.x;
    const int b = blockIdx.x >> 5;
    const int cg = blockIdx.x & 31;
    const int hw4 = t * 4;

    const int4 iv = *(const int4*)&ws_idx[b * HW + hw4];
    const float* zb = z + (size_t)b * (CDIM * HW) + hw4;
    float* ob = out_zq + (size_t)b * (CDIM * HW) + hw4;
    const float* e0p = emb + (size_t)iv.x * CDIM;
    const float* e1p = emb + (size_t)iv.y * CDIM;
    const float* e2p = emb + (size_t)iv.z * CDIM;
    const float* e3p = emb + (size_t)iv.w * CDIM;

    float lsum = 0.f;
#pragma unroll
    for (int c = cg * 8; c < cg * 8 + 8; ++c) {
        float4 zv = *(const float4*)&zb[(size_t)c * HW];
        float d0 = e0p[c] - zv.x;
        float d1 = e1p[c] - zv.y;
        float d2 = e2p[c] - zv.z;
        float d3 = e3p[c] - zv.w;
        float4 ov = { zv.x + d0, zv.y + d1, zv.z + d2, zv.w + d3 };
        *(float4*)&ob[(size_t)c * HW] = ov;
        lsum = fmaf(d0, d0, lsum);
        lsum = fmaf(d1, d1, lsum);
        lsum = fmaf(d2, d2, lsum);
        lsum = fmaf(d3, d3, lsum);
    }
#pragma unroll
    for (int off = 32; off > 0; off >>= 1) lsum += __shfl_down(lsum, off);
    __shared__ float wsum[4];
    if ((t & 63) == 0) wsum[t >> 6] = lsum;
    __syncthreads();
    if (t == 0) partials[blockIdx.x] = (wsum[0] + wsum[1]) + (wsum[2] + wsum[3]);
}

// ---- kernel 6: finalize loss = 1.25 * mean(diff^2) over 1024 partials ----
__global__ void loss_kernel(const float* __restrict__ partials, float* __restrict__ out_loss) {
    const int t = threadIdx.x;
    float4 v4 = *(const float4*)&partials[t * 4];
    float v = (v4.x + v4.y) + (v4.z + v4.w);
#pragma unroll
    for (int off = 32; off > 0; off >>= 1) v += __shfl_down(v, off);
    __shared__ float wsum[4];
    if ((t & 63) == 0) wsum[t >> 6] = v;
    __syncthreads();
    if (t == 0) {
        float total = (wsum[0] + wsum[1]) + (wsum[2] + wsum[3]);
        out_loss[0] = 1.25f * total / 8388608.0f;
    }
}

extern "C" void kernel_launch(void* const* d_in, const int* in_sizes, int n_in,
                              void* d_out, int out_size, void* d_ws, size_t ws_size,
                              hipStream_t stream) {
    const float* z   = (const float*)d_in[0];
    const float* emb = (const float*)d_in[1];
    float* out = (float*)d_out;

    // A (fp16 [32768][512] = 32 MB) lives in the zq region of d_out; gather overwrites it last.
    f16* A = (f16*)d_out;

    char* w = (char*)d_ws;
    float*  e2       = (float*)(w + 0);            // 4 KB
    float*  z2       = (float*)(w + 4096);         // 128 KB
    f16*    e16      = (f16*)(w + 135168);         // 1 MB
    float4* tile_red = (float4*)(w + 1183744);     // 4 MB
    int*    ws_idx   = (int*)(w + 5378048);        // 128 KB
    float*  partials = (float*)(w + 5509120);      // 4 KB

    // z_t: exact fp32 transposed z for coalesced rescore (guarded by ws_size)
    const size_t zt_need = ZT_OFF + (size_t)NROWS * CDIM * sizeof(float);
    float* z_t = (ws_size >= zt_need) ? (float*)(w + ZT_OFF) : nullptr;

    hipLaunchKernelGGL(prep_kernel, dim3(1152), dim3(256), 0, stream,
                       z, emb, A, z2, e2, e16, z_t);
    hipLaunchKernelGGL(gemm_argmin_kernel, dim3(1024), dim3(512), 0, stream,
                       A, e16, z2, e2, tile_red);
    hipLaunchKernelGGL(rescore_kernel, dim3(512), dim3(256), 0, stream,
                       z, emb, z2, e2, tile_red, z_t, out + IDX_OFF, ws_idx);
    hipLaunchKernelGGL(gather_kernel, dim3(1024), dim3(256), 0, stream,
                       z, emb, ws_idx, out, partials);
    hipLaunchKernelGGL(loss_kernel, dim3(1), dim3(256), 0, stream,
                       partials, out + LOSS_OFF);
}

// Round 12
// 194.191 us; speedup vs baseline: 1.3931x; 1.0822x over previous
//
#include <hip/hip_runtime.h>

#define CDIM 256
#define HW 1024            // 32*32
#define NROWS 32768        // 32*1024
#define KCODES 1024
#define ZQ_ELEMS 8388608   // 32*256*1024
#define IDX_OFF ZQ_ELEMS
#define LOSS_OFF (ZQ_ELEMS + NROWS)
#define FLT_BIG 3.402823466e+38f
#define ZT_OFF 5513232ull  // 16B-aligned; z_t fp32 [32768][256] = 32 MB (ws-guarded)

typedef _Float16 f16;
typedef _Float16 f16x8 __attribute__((ext_vector_type(8)));
typedef float f32x4 __attribute__((ext_vector_type(4)));
typedef float f32x16 __attribute__((ext_vector_type(16)));

// async global->LDS, 16 B per lane; LDS dest = wave-uniform base + lane*16
__device__ __forceinline__ void glds16(const void* g, void* l) {
    __builtin_amdgcn_global_load_lds(
        (const __attribute__((address_space(1))) unsigned int*)g,
        (__attribute__((address_space(3))) unsigned int*)l,
        16, 0, 0);
}

__device__ __forceinline__ unsigned int pack_f16x2(f16 a, f16 b) {
    unsigned short ua = *(unsigned short*)&a, ub = *(unsigned short*)&b;
    return (unsigned int)ua | ((unsigned int)ub << 16);
}

// ---- numpy-bit-exact pairwise sum of squares over 256 contiguous floats ----
__device__ __forceinline__ float np_sumsq_256(const float* __restrict__ a) {
    float half[2];
#pragma unroll
    for (int h = 0; h < 2; ++h) {
        const float* p = a + h * 128;
        float r[8];
#pragma unroll
        for (int j = 0; j < 8; ++j) r[j] = __fmul_rn(p[j], p[j]);
#pragma unroll
        for (int i = 8; i < 128; i += 8) {
#pragma unroll
            for (int j = 0; j < 8; ++j)
                r[j] = __fadd_rn(r[j], __fmul_rn(p[i + j], p[i + j]));
        }
        float ta = __fadd_rn(__fadd_rn(r[0], r[1]), __fadd_rn(r[2], r[3]));
        float tb = __fadd_rn(__fadd_rn(r[4], r[5]), __fadd_rn(r[6], r[7]));
        half[h] = __fadd_rn(ta, tb);
    }
    return __fadd_rn(half[0], half[1]);
}

__device__ __forceinline__ bool lex_lt(float s1, int k1, float s2, int k2) {
    return (s1 < s2) || (s1 == s2 && k1 < k2);
}

__device__ __forceinline__ void top2_merge(float& a1, int& ka1, float& a2, int& ka2,
                                           float b1, int kb1, float b2, int kb2) {
    if (lex_lt(b1, kb1, a1, ka1)) {
        float t1 = a1; int tk1 = ka1;
        a1 = b1; ka1 = kb1;
        if (lex_lt(b2, kb2, t1, tk1)) { a2 = b2; ka2 = kb2; }
        else                          { a2 = t1; ka2 = tk1; }
    } else {
        if (lex_lt(b1, kb1, a2, ka2)) { a2 = b1; ka2 = kb1; }
    }
}

// ---- kernel 1 (fused): blocks 0..1023 = z prep, 1024..1151 = emb prep ----
// z path additionally writes z_t (exact fp32 transposed z) when ws has room.
__global__ void __launch_bounds__(256)
prep_kernel(const float* __restrict__ z, const float* __restrict__ emb,
            f16* __restrict__ A, float* __restrict__ z2,
            float* __restrict__ e2, f16* __restrict__ e16,
            float* __restrict__ z_t) {
    const int t = threadIdx.x;
    if (blockIdx.x >= 1024) {
        // ---- emb path ----
        const int gid = (blockIdx.x - 1024) * 256 + t;    // 0..32767
        const int k = gid >> 5, seg = gid & 31;           // seg covers 8 c
        const float* src = emb + (size_t)k * CDIM + seg * 8;
        float4 v0 = *(const float4*)src;
        float4 v1 = *(const float4*)(src + 4);
        float s[8] = { v0.x, v0.y, v0.z, v0.w, v1.x, v1.y, v1.z, v1.w };
        f16 h[8], l[8];
#pragma unroll
        for (int j = 0; j < 8; ++j) {
            float sv = s[j] * 1024.0f;
            h[j] = (f16)sv;
            float r = __fsub_rn(sv, (float)h[j]);
            l[j] = (f16)r;
        }
        uint4 hv, lv;
        hv.x = pack_f16x2(h[0], h[1]); hv.y = pack_f16x2(h[2], h[3]);
        hv.z = pack_f16x2(h[4], h[5]); hv.w = pack_f16x2(h[6], h[7]);
        lv.x = pack_f16x2(l[0], l[1]); lv.y = pack_f16x2(l[2], l[3]);
        lv.z = pack_f16x2(l[4], l[5]); lv.w = pack_f16x2(l[6], l[7]);
        *(uint4*)(e16 + (size_t)k * 512 + seg * 8) = hv;
        *(uint4*)(e16 + (size_t)k * 512 + 256 + seg * 8) = lv;
        if (seg == 0) e2[k] = np_sumsq_256(emb + (size_t)k * CDIM);
        return;
    }
    // ---- z path ----
    __shared__ __align__(16) float z_lds[32 * 260];
    const int n0 = blockIdx.x * 32;
    const int b = n0 >> 10, hw0 = n0 & 1023;
    const float* zbase = z + (size_t)b * (CDIM * HW) + hw0;
#pragma unroll
    for (int p = 0; p < 8; ++p) {
        int id = p * 256 + t;
        int c = id >> 3;
        int m4 = id & 7;
        float4 v = *(const float4*)(zbase + (size_t)c * HW + m4 * 4);
        z_lds[(m4 * 4 + 0) * 260 + c] = v.x;
        z_lds[(m4 * 4 + 1) * 260 + c] = v.y;
        z_lds[(m4 * 4 + 2) * 260 + c] = v.z;
        z_lds[(m4 * 4 + 3) * 260 + c] = v.w;
    }
    __syncthreads();
    if (t < 32) z2[n0 + t] = np_sumsq_256(&z_lds[t * 260]);

    if (z_t) {
        // exact fp32 transposed copy: row n contiguous (coalesced float4 stores)
#pragma unroll
        for (int p = 0; p < 8; ++p) {
            int id = p * 256 + t;
            int m = id >> 6;             // row 0..31
            int c4 = (id & 63) * 4;      // 0..252
            float4 v = { z_lds[m * 260 + c4],     z_lds[m * 260 + c4 + 1],
                         z_lds[m * 260 + c4 + 2], z_lds[m * 260 + c4 + 3] };
            *(float4*)&z_t[(size_t)(n0 + m) * CDIM + c4] = v;
        }
    }

    const int lane = t & 63, wave = t >> 6;
    const int half = lane >> 5;       // 0 = hi, 1 = lo
    const int seg = lane & 31;        // 8 c per seg
#pragma unroll
    for (int rr = 0; rr < 8; ++rr) {
        const int m = wave * 8 + rr;
        const float* zr = &z_lds[m * 260 + seg * 8];
        f16 o[8];
#pragma unroll
        for (int j = 0; j < 8; ++j) {
            float sv = zr[j] * 16.0f;
            f16 hh = (f16)sv;
            if (half) {
                float r = __fsub_rn(sv, (float)hh);
                o[j] = (f16)r;
            } else {
                o[j] = hh;
            }
        }
        uint4 ov;
        ov.x = pack_f16x2(o[0], o[1]); ov.y = pack_f16x2(o[2], o[3]);
        ov.z = pack_f16x2(o[4], o[5]); ov.w = pack_f16x2(o[6], o[7]);
        *(uint4*)(A + (size_t)(n0 + m) * 512 + half * 256 + seg * 8) = ov;
    }
}

// ---- kernel 3: MFMA GEMM (codes-as-M, 32x32x16) + lane-local top2 ----
// WIDE-Z tile (R10-verified shell): 128 codes x 256 z-rows, 8 waves,
// 2-barrier BK=32 dbuf, LDS 72.5 KB -> 2 blocks/CU, __launch_bounds__(512,2)
// (VGPR cap ~128; (512,4)/(256,4) -> 64-cap SPILL, R5/R9).
// THREE-TERM DECOMPOSITION: dot*2^14 = (zh+zl)*(eh+el) with the
// second-order zl*el term DROPPED (distance error ~1e-7, 1000x below the
// 1e-4 rescore margin; approx scores are only a candidate filter -- the
// exact fp32 rescore decides).
//   pass1 (all 16 chunks): z[kk] * eh[kk&7]   (zh*eh for kk<8, zl*eh for kk>=8)
//   pass2 (kk<8 only):     zh[kk] * el[kk]
// K_eff 1024 -> 768: 25% fewer MFMAs, 12.5% fewer staged bytes.
// All barriers unconditional; staging/MFMA predicates are block-uniform
// (loop-counter based) -- no divergent-barrier hazard.
// Grid 1024: Ntile=bid&127, Mtile=bid>>7 (8 same-z blocks == mod 8 -> same
// XCD). Swizzle (rule 21, both sides) unchanged. Epilogue unchanged.
// acc = dot * 2^14 -> 2*dot = acc * 2^-13.
__global__ void __launch_bounds__(512, 2)
gemm_argmin_kernel(const f16* __restrict__ A, const f16* __restrict__ B,
                   const float* __restrict__ z2, const float* __restrict__ e2,
                   float4* __restrict__ tile_red) {
    __shared__ __align__(16) f16 c1_lds[2][128 * 32];   // eh chunks (16 KB)
    __shared__ __align__(16) f16 c2_lds[2][128 * 32];   // el chunks, kk<8 (16 KB)
    __shared__ __align__(16) f16 z_lds[2][256 * 32];    // z rows (32 KB)
    __shared__ __align__(16) float4 red_lds[2 * 256];   // 8 KB
    __shared__ float e2_lds[128];                       // 0.5 KB

    const int t = threadIdx.x;
    const int lane = t & 63, wave = t >> 6;     // wave 0..7
    const int Ntile = blockIdx.x & 127;         // z-row tile (128 total, 256 rows each)
    const int Mtile = blockIdx.x >> 7;          // code tile (8 total)
    const int wc = (wave & 1) * 64;             // code offset in tile
    const int wz = (wave >> 1) * 64;            // zrow offset in tile (4 quarters)
    const int c31 = lane & 31, hhalf = lane >> 5;
    const int gsw = (c31 >> 1) & 3;             // read-side bank swizzle key

    if (t < 128) e2_lds[t] = e2[Mtile * 128 + t];

    // staging: wave w stages c1 seg w, c2 seg w (kk<8), z segs 2w and 2w+1.
    const char* Cbase = (const char*)(B + (size_t)Mtile * 128 * 512);  // codebook f16
    const char* Zbase = (const char*)(A + (size_t)Ntile * 256 * 512);  // z f16
    const int lrow = lane >> 2;
    const int lsw = ((lane & 3) ^ ((lrow >> 1) & 3)) * 16;
    const char* cg  = Cbase + (size_t)(wave * 16 + lrow) * 1024 + lsw;
    const char* zg0 = Zbase + (size_t)((2 * wave) * 16 + lrow) * 1024 + lsw;
    const char* zg1 = Zbase + (size_t)((2 * wave + 1) * 16 + lrow) * 1024 + lsw;
    const int woffc  = wave * 512;              // f16 offset of wave's c segment
    const int woffz0 = (2 * wave) * 512;
    const int woffz1 = (2 * wave + 1) * 512;

    // per-lane ds_read bases (f16 index): row*32, plus swizzled granule per ks
    int crow32[2], zrow32[2], g8[2];
#pragma unroll
    for (int i = 0; i < 2; ++i) crow32[i] = (wc + i * 32 + c31) * 32;
#pragma unroll
    for (int j = 0; j < 2; ++j) zrow32[j] = (wz + j * 32 + c31) * 32;
#pragma unroll
    for (int ks = 0; ks < 2; ++ks) g8[ks] = ((2 * ks + hhalf) ^ gsw) * 8;

    f32x16 acc[2][2] = {};

    // preload chunk 0 into buf 0: c1 = eh[0], c2 = el[0], z chunk 0
    glds16(cg,        &c1_lds[0][woffc]);
    glds16(cg + 512,  &c2_lds[0][woffc]);
    glds16(zg0,       &z_lds[0][woffz0]);
    glds16(zg1,       &z_lds[0][woffz1]);
    __syncthreads();   // vmcnt(0) drain: chunk 0 resident

    for (int kk = 0; kk < 16; ++kk) {
        const int buf = kk & 1;
        if (kk < 15) {
            const int nb = buf ^ 1;
            const int kn = kk + 1;
            glds16(cg + (kn & 7) * 64, &c1_lds[nb][woffc]);   // eh chunk kn&7
            if (kn < 8)
                glds16(cg + 512 + kn * 64, &c2_lds[nb][woffc]); // el chunk kn
            glds16(zg0 + kn * 64, &z_lds[nb][woffz0]);
            glds16(zg1 + kn * 64, &z_lds[nb][woffz1]);
        }

#pragma unroll
        for (int ks = 0; ks < 2; ++ks) {
            f16x8 zf[2], cf1[2];
#pragma unroll
            for (int j = 0; j < 2; ++j)
                zf[j] = *(const f16x8*)&z_lds[buf][zrow32[j] + g8[ks]];
#pragma unroll
            for (int i = 0; i < 2; ++i)
                cf1[i] = *(const f16x8*)&c1_lds[buf][crow32[i] + g8[ks]];
#pragma unroll
            for (int i = 0; i < 2; ++i)
#pragma unroll
                for (int j = 0; j < 2; ++j)
                    acc[i][j] = __builtin_amdgcn_mfma_f32_32x32x16_f16(cf1[i], zf[j], acc[i][j], 0, 0, 0);
            if (kk < 8) {
                f16x8 cf2[2];
#pragma unroll
                for (int i = 0; i < 2; ++i)
                    cf2[i] = *(const f16x8*)&c2_lds[buf][crow32[i] + g8[ks]];
#pragma unroll
                for (int i = 0; i < 2; ++i)
#pragma unroll
                    for (int j = 0; j < 2; ++j)
                        acc[i][j] = __builtin_amdgcn_mfma_f32_32x32x16_f16(cf2[i], zf[j], acc[i][j], 0, 0, 0);
            }
        }
        __syncthreads();   // drains vmcnt: chunk kk+1 resident; buf^1 safe next iter
    }

    // ---- epilogue: d = fl(fl(z2+e2) - fl(acc*2^-13)); lane-local top2 over 32 codes ----
#pragma unroll
    for (int j = 0; j < 2; ++j) {
        const float z2v = z2[Ntile * 256 + wz + j * 32 + c31];
        float s1 = FLT_BIG, s2 = FLT_BIG;
        int k1 = KCODES, k2 = KCODES;
#pragma unroll
        for (int i = 0; i < 2; ++i) {
            const int cbase = wc + i * 32 + 4 * hhalf;
#pragma unroll
            for (int r = 0; r < 16; ++r) {
                const int clocal = cbase + (r & 3) + 8 * (r >> 2);
                const float e2r = e2_lds[clocal];
                const float d = __fsub_rn(__fadd_rn(z2v, e2r),
                                          __fmul_rn(acc[i][j][r], 1.220703125e-4f));
                const int kc = Mtile * 128 + clocal;
                if (lex_lt(d, kc, s1, k1)) { s2 = s1; k2 = k1; s1 = d; k1 = kc; }
                else if (lex_lt(d, kc, s2, k2)) { s2 = d; k2 = kc; }
            }
        }
        // partner merge: lanes l and l^32 share the same z-row, complementary codes
        float b1 = __shfl_xor(s1, 32); int kb1 = __shfl_xor(k1, 32);
        float b2 = __shfl_xor(s2, 32); int kb2 = __shfl_xor(k2, 32);
        top2_merge(s1, k1, s2, k2, b1, kb1, b2, kb2);
        if (hhalf == 0) {
            float4 st;
            st.x = s1; st.y = __int_as_float(k1);
            st.z = s2; st.w = __int_as_float(k2);
            red_lds[(wave & 1) * 256 + wz + j * 32 + c31] = st;
        }
    }
    __syncthreads();
    if (t < 256) {
        float4 a = red_lds[t];
        float4 b = red_lds[256 + t];
        float a1 = a.x, a2 = a.z; int ka1 = __float_as_int(a.y), ka2 = __float_as_int(a.w);
        top2_merge(a1, ka1, a2, ka2, b.x, __float_as_int(b.y), b.z, __float_as_int(b.w));
        float4 o;
        o.x = a1; o.y = __int_as_float(ka1); o.z = a2; o.w = __int_as_float(ka2);
        tile_red[(size_t)(Ntile * 256 + t) * 8 + Mtile] = o;
    }
}

// ---- kernel 4: candidate reduce + exact fp32 rescore, 4 lanes per row ----
// (R8-verified: 4 lanes/row TLP + z_t coalesced reads; exact rescore decides.)
__global__ void __launch_bounds__(256)
rescore_kernel(const float* __restrict__ z, const float* __restrict__ emb,
               const float* __restrict__ z2, const float* __restrict__ e2,
               const float4* __restrict__ tile_red, const float* __restrict__ z_t,
               float* __restrict__ out_idx_f, int* __restrict__ ws_idx) {
    const int gid = blockIdx.x * 256 + threadIdx.x;
    const int n = gid >> 2, q = gid & 3;

    float s[4]; int k[4];
    const float4 v0 = tile_red[(size_t)n * 8 + q * 2];
    const float4 v1 = tile_red[(size_t)n * 8 + q * 2 + 1];
    s[0] = v0.x; k[0] = __float_as_int(v0.y);
    s[1] = v0.z; k[1] = __float_as_int(v0.w);
    s[2] = v1.x; k[2] = __float_as_int(v1.y);
    s[3] = v1.z; k[3] = __float_as_int(v1.w);

    float s1 = FLT_BIG; int k1 = KCODES;
#pragma unroll
    for (int i = 0; i < 4; ++i)
        if (lex_lt(s[i], k[i], s1, k1)) { s1 = s[i]; k1 = k[i]; }
    // merge global top1 across the 4-lane group (masks 1,2 stay in-group)
#pragma unroll
    for (int m = 1; m <= 2; m <<= 1) {
        float bs = __shfl_xor(s1, m); int bk2 = __shfl_xor(k1, m);
        if (lex_lt(bs, bk2, s1, k1)) { s1 = bs; k1 = bk2; }
    }
    const float thr = s1 + 1.0e-4f;
    int cnt = 0;
#pragma unroll
    for (int i = 0; i < 4; ++i) cnt += (s[i] <= thr) ? 1 : 0;
    cnt += __shfl_xor(cnt, 1);
    cnt += __shfl_xor(cnt, 2);

    int bk = k1;
    if (cnt > 1) {
        int kk[4];
#pragma unroll
        for (int i = 0; i < 4; ++i) kk[i] = (s[i] <= thr) ? k[i] : k1;
        float accs[4] = { 0.f, 0.f, 0.f, 0.f };
        if (z_t) {
            const float* zr = z_t + (size_t)n * CDIM;
            for (int c0 = 0; c0 < 256; c0 += 4) {
                const float4 zv = *(const float4*)&zr[c0];
#pragma unroll
                for (int j = 0; j < 4; ++j) {
                    float4 ev = *(const float4*)&emb[(size_t)kk[j] * CDIM + c0];
                    accs[j] = fmaf(zv.x, ev.x, accs[j]);
                    accs[j] = fmaf(zv.y, ev.y, accs[j]);
                    accs[j] = fmaf(zv.z, ev.z, accs[j]);
                    accs[j] = fmaf(zv.w, ev.w, accs[j]);
                }
            }
        } else {
            const float* zb = z + (size_t)(n >> 10) * (CDIM * HW) + (n & 1023);
            for (int c0 = 0; c0 < 256; c0 += 4) {
                float zc0 = zb[(size_t)(c0 + 0) * HW];
                float zc1 = zb[(size_t)(c0 + 1) * HW];
                float zc2 = zb[(size_t)(c0 + 2) * HW];
                float zc3 = zb[(size_t)(c0 + 3) * HW];
#pragma unroll
                for (int j = 0; j < 4; ++j) {
                    float4 ev = *(const float4*)&emb[(size_t)kk[j] * CDIM + c0];
                    accs[j] = fmaf(zc0, ev.x, accs[j]);
                    accs[j] = fmaf(zc1, ev.y, accs[j]);
                    accs[j] = fmaf(zc2, ev.z, accs[j]);
                    accs[j] = fmaf(zc3, ev.w, accs[j]);
                }
            }
        }
        float bd = FLT_BIG; bk = KCODES;
        const float z2n = z2[n];
#pragma unroll
        for (int j = 0; j < 4; ++j) {
            float d = __fsub_rn(__fadd_rn(z2n, e2[kk[j]]), accs[j] + accs[j]);
            if (lex_lt(d, kk[j], bd, bk)) { bd = d; bk = kk[j]; }
        }
        // merge exact best across the 4-lane group
#pragma unroll
        for (int m = 1; m <= 2; m <<= 1) {
            float bs = __shfl_xor(bd, m); int bb = __shfl_xor(bk, m);
            if (lex_lt(bs, bb, bd, bk)) { bd = bs; bk = bb; }
        }
    }
    if (q == 0) {
        out_idx_f[n] = (float)bk;
        ws_idx[n] = bk;
    }
}

// ---- kernel 5: gather z_q, write z_q_st, partial loss sums ----
__global__ void __launch_bounds__(256)
gather_kernel(const float* __restrict__ z, const float* __restrict__ emb,
              const int* __restrict__ ws_idx, float* __restrict__ out_zq,
              float* __restrict__ partials) {
    const int t = threadIdx.x;
    const int b = blockIdx.x >> 5;
    const int cg = blockIdx.x & 31;
    const int hw4 = t * 4;

    const int4 iv = *(const int4*)&ws_idx[b * HW + hw4];
    const float* zb = z + (size_t)b * (CDIM * HW) + hw4;
    float* ob = out_zq + (size_t)b * (CDIM * HW) + hw4;
    const float* e0p = emb + (size_t)iv.x * CDIM;
    const float* e1p = emb + (size_t)iv.y * CDIM;
    const float* e2p = emb + (size_t)iv.z * CDIM;
    const float* e3p = emb + (size_t)iv.w * CDIM;

    float lsum = 0.f;
#pragma unroll
    for (int c = cg * 8; c < cg * 8 + 8; ++c) {
        float4 zv = *(const float4*)&zb[(size_t)c * HW];
        float d0 = e0p[c] - zv.x;
        float d1 = e1p[c] - zv.y;
        float d2 = e2p[c] - zv.z;
        float d3 = e3p[c] - zv.w;
        float4 ov = { zv.x + d0, zv.y + d1, zv.z + d2, zv.w + d3 };
        *(float4*)&ob[(size_t)c * HW] = ov;
        lsum = fmaf(d0, d0, lsum);
        lsum = fmaf(d1, d1, lsum);
        lsum = fmaf(d2, d2, lsum);
        lsum = fmaf(d3, d3, lsum);
    }
#pragma unroll
    for (int off = 32; off > 0; off >>= 1) lsum += __shfl_down(lsum, off);
    __shared__ float wsum[4];
    if ((t & 63) == 0) wsum[t >> 6] = lsum;
    __syncthreads();
    if (t == 0) partials[blockIdx.x] = (wsum[0] + wsum[1]) + (wsum[2] + wsum[3]);
}

// ---- kernel 6: finalize loss = 1.25 * mean(diff^2) over 1024 partials ----
__global__ void loss_kernel(const float* __restrict__ partials, float* __restrict__ out_loss) {
    const int t = threadIdx.x;
    float4 v4 = *(const float4*)&partials[t * 4];
    float v = (v4.x + v4.y) + (v4.z + v4.w);
#pragma unroll
    for (int off = 32; off > 0; off >>= 1) v += __shfl_down(v, off);
    __shared__ float wsum[4];
    if ((t & 63) == 0) wsum[t >> 6] = v;
    __syncthreads();
    if (t == 0) {
        float total = (wsum[0] + wsum[1]) + (wsum[2] + wsum[3]);
        out_loss[0] = 1.25f * total / 8388608.0f;
    }
}

extern "C" void kernel_launch(void* const* d_in, const int* in_sizes, int n_in,
                              void* d_out, int out_size, void* d_ws, size_t ws_size,
                              hipStream_t stream) {
    const float* z   = (const float*)d_in[0];
    const float* emb = (const float*)d_in[1];
    float* out = (float*)d_out;

    // A (fp16 [32768][512] = 32 MB) lives in the zq region of d_out; gather overwrites it last.
    f16* A = (f16*)d_out;

    char* w = (char*)d_ws;
    float*  e2       = (float*)(w + 0);            // 4 KB
    float*  z2       = (float*)(w + 4096);         // 128 KB
    f16*    e16      = (f16*)(w + 135168);         // 1 MB
    float4* tile_red = (float4*)(w + 1183744);     // 4 MB
    int*    ws_idx   = (int*)(w + 5378048);        // 128 KB
    float*  partials = (float*)(w + 5509120);      // 4 KB

    // z_t: exact fp32 transposed z for coalesced rescore (guarded by ws_size)
    const size_t zt_need = ZT_OFF + (size_t)NROWS * CDIM * sizeof(float);
    float* z_t = (ws_size >= zt_need) ? (float*)(w + ZT_OFF) : nullptr;

    hipLaunchKernelGGL(prep_kernel, dim3(1152), dim3(256), 0, stream,
                       z, emb, A, z2, e2, e16, z_t);
    hipLaunchKernelGGL(gemm_argmin_kernel, dim3(1024), dim3(512), 0, stream,
                       A, e16, z2, e2, tile_red);
    hipLaunchKernelGGL(rescore_kernel, dim3(512), dim3(256), 0, stream,
                       z, emb, z2, e2, tile_red, z_t, out + IDX_OFF, ws_idx);
    hipLaunchKernelGGL(gather_kernel, dim3(1024), dim3(256), 0, stream,
                       z, emb, ws_idx, out, partials);
    hipLaunchKernelGGL(loss_kernel, dim3(1), dim3(256), 0, stream,
                       partials, out + LOSS_OFF);
}